// Round 22
// baseline (109.657 us; speedup 1.0000x reference)
//
#include <hip/hip_runtime.h>
#include <math.h>
#include <stdint.h>

// Problem dims (fixed)
#define BATCH 4
#define CQ 256      // x channels
#define P 4096      // query positions (64*64)
#define CC 512      // context channels
#define PC 1024     // kv positions (32*32)
#define HID 512     // HEADS*DIM_HEAD
#define HEADS 8
#define DH 64

// Fold attention scale 1/sqrt(64) * log2(e) into Q so softmax uses exp2.
#define QSCALE 0.180336880111113703f

typedef __attribute__((ext_vector_type(8))) __fp16 f16x8;
typedef __attribute__((ext_vector_type(2))) __fp16 f16x2;
typedef __attribute__((ext_vector_type(4))) float f32x4;
typedef __attribute__((ext_vector_type(4))) unsigned int u32x4;

union H2U { f16x2 h; uint32_t u; };
union F8U { uint32_t u[4]; f16x8 v; };

__device__ __forceinline__ uint32_t pkh(float a, float b) {
    H2U z; z.h = __builtin_amdgcn_cvt_pkrtz(a, b); return z.u;
}
__device__ __forceinline__ f16x2 upk(uint32_t w) { H2U z; z.u = w; return z.h; }

#if __has_builtin(__builtin_amdgcn_exp2f)
#define EXP2(x) __builtin_amdgcn_exp2f(x)
#else
#define EXP2(x) exp2f(x)
#endif

#define MFMA16(a, b, c) __builtin_amdgcn_mfma_f32_16x16x32_f16(a, b, c, 0, 0, 0)

// async global -> LDS, 16B per lane. lds base must be wave-uniform.
__device__ __forceinline__ void gl_lds16(const unsigned short* g, unsigned short* l) {
    __builtin_amdgcn_global_load_lds(
        (const __attribute__((address_space(1))) unsigned int*)g,
        (__attribute__((address_space(3))) unsigned int*)l, 16, 0, 0);
}

// ---------------------------------------------------------------------------
// Split weights, fp16 HI only (float4-vectorized). (unchanged)
// ---------------------------------------------------------------------------
__global__ __launch_bounds__(256) void split_all(
    const float* __restrict__ Wq, const float* __restrict__ Wk,
    const float* __restrict__ Wv, const float* __restrict__ Wo,
    unsigned short* __restrict__ wqh, unsigned short* __restrict__ wkh,
    unsigned short* __restrict__ wvh, unsigned short* __restrict__ woh)
{
    const int bid = blockIdx.x;
    const int t = threadIdx.x;
    const float* src; unsigned short* dh; int i4; float sc = 1.f; int ksh;
    if (bid < 128)      { src = Wq; dh = wqh; i4 = bid * 256 + t; sc = QSCALE; ksh = 8; }
    else if (bid < 384) { src = Wk; dh = wkh; i4 = (bid - 128) * 256 + t; ksh = 9; }
    else if (bid < 640) { src = Wv; dh = wvh; i4 = (bid - 384) * 256 + t; ksh = 9; }
    else                { src = Wo; dh = woh; i4 = (bid - 640) * 256 + t; ksh = 0; }
    float4 v = *reinterpret_cast<const float4*>(src + (size_t)i4 * 4);
    uint2 hh;
    hh.x = pkh(sc * v.x, sc * v.y);
    hh.y = pkh(sc * v.z, sc * v.w);
    if (ksh) {
        const int lin = i4 * 4;
        const int m = lin >> ksh;
        const int k = lin & ((1 << ksh) - 1);
        const size_t off = ((size_t)(k >> 3) * HID + m) * 8 + (k & 7);
        *reinterpret_cast<uint2*>(dh + off) = hh;
    } else {
        *reinterpret_cast<uint2*>(dh + (size_t)i4 * 4) = hh;
    }
}

// ---------------------------------------------------------------------------
// Fused Q + K + V projections (R19/R21 verified shape, unchanged).
// ---------------------------------------------------------------------------
__global__ __launch_bounds__(256) void proj_qkv(
    const unsigned short* __restrict__ wqh_, const unsigned short* __restrict__ wkh_,
    const unsigned short* __restrict__ wvh_,
    const float* __restrict__ x_, const float* __restrict__ ctx_,
    unsigned short* __restrict__ qh_,
    unsigned short* __restrict__ kh_, unsigned short* __restrict__ vh_)
{
    const int b = blockIdx.z;
    const int bx = blockIdx.x;
    const int wid = threadIdx.x >> 6;
    const int l = threadIdx.x & 63;
    const int ln = l & 15, g = l >> 4;
    const int mb = blockIdx.y * 128 + 64 * (wid & 1);

    f32x4 acc[4][2];
    #pragma unroll
    for (int mt = 0; mt < 4; ++mt)
        #pragma unroll
        for (int nt = 0; nt < 2; ++nt) {
            f32x4 z = {0.f, 0.f, 0.f, 0.f};
            acc[mt][nt] = z;
        }

    int mode;        // 0=Q, 1=K, 2=V
    int nb;
    if (bx < 64) {
        mode = 0;
        nb = bx * 64 + 32 * (wid >> 1);
        const float* xb = x_ + (size_t)b * CQ * P;
        #pragma unroll 2
        for (int k0 = 0; k0 < CQ; k0 += 32) {
            const int kq = (k0 >> 3) + g;
            f16x8 ah[4];
            #pragma unroll
            for (int mt = 0; mt < 4; ++mt)
                ah[mt] = *reinterpret_cast<const f16x8*>(
                    wqh_ + ((size_t)kq * HID + mb + 16 * mt + ln) * 8);
            #pragma unroll
            for (int nt = 0; nt < 2; ++nt) {
                const int pos = nb + 16 * nt + ln;
                float v0 = xb[(size_t)(8 * kq + 0) * P + pos];
                float v1 = xb[(size_t)(8 * kq + 1) * P + pos];
                float v2 = xb[(size_t)(8 * kq + 2) * P + pos];
                float v3 = xb[(size_t)(8 * kq + 3) * P + pos];
                float v4 = xb[(size_t)(8 * kq + 4) * P + pos];
                float v5 = xb[(size_t)(8 * kq + 5) * P + pos];
                float v6 = xb[(size_t)(8 * kq + 6) * P + pos];
                float v7 = xb[(size_t)(8 * kq + 7) * P + pos];
                F8U bh;
                bh.u[0] = pkh(v0, v1); bh.u[1] = pkh(v2, v3);
                bh.u[2] = pkh(v4, v5); bh.u[3] = pkh(v6, v7);
                #pragma unroll
                for (int mt = 0; mt < 4; ++mt)
                    acc[mt][nt] = MFMA16(ah[mt], bh.v, acc[mt][nt]);
            }
        }
    } else {
        const int u = bx - 64;
        mode = 1 + (u >> 4);
        nb = (u & 15) * 64 + 32 * (wid >> 1);
        const unsigned short* Ah = (mode == 2) ? wvh_ : wkh_;
        const float* cb = ctx_ + (size_t)b * CC * PC;
        #pragma unroll 2
        for (int k0 = 0; k0 < CC; k0 += 32) {
            const int kq = (k0 >> 3) + g;
            f16x8 ah[4];
            #pragma unroll
            for (int mt = 0; mt < 4; ++mt)
                ah[mt] = *reinterpret_cast<const f16x8*>(
                    Ah + ((size_t)kq * HID + mb + 16 * mt + ln) * 8);
            #pragma unroll
            for (int nt = 0; nt < 2; ++nt) {
                const int pos = nb + 16 * nt + ln;
                float v0 = cb[(size_t)(8 * kq + 0) * PC + pos];
                float v1 = cb[(size_t)(8 * kq + 1) * PC + pos];
                float v2 = cb[(size_t)(8 * kq + 2) * PC + pos];
                float v3 = cb[(size_t)(8 * kq + 3) * PC + pos];
                float v4 = cb[(size_t)(8 * kq + 4) * PC + pos];
                float v5 = cb[(size_t)(8 * kq + 5) * PC + pos];
                float v6 = cb[(size_t)(8 * kq + 6) * PC + pos];
                float v7 = cb[(size_t)(8 * kq + 7) * PC + pos];
                F8U bh;
                bh.u[0] = pkh(v0, v1); bh.u[1] = pkh(v2, v3);
                bh.u[2] = pkh(v4, v5); bh.u[3] = pkh(v6, v7);
                #pragma unroll
                for (int mt = 0; mt < 4; ++mt)
                    acc[mt][nt] = MFMA16(ah[mt], bh.v, acc[mt][nt]);
            }
        }
    }

    if (mode == 0) {
        #pragma unroll
        for (int mt = 0; mt < 4; ++mt) {
            const int m0 = mb + 16 * mt + 4 * g;
            const int h = m0 >> 6, cl2 = m0 & 63;
            #pragma unroll
            for (int nt = 0; nt < 2; ++nt) {
                const int pos = nb + 16 * nt + ln;
                uint2 hh;
                hh.x = pkh(acc[mt][nt][0], acc[mt][nt][1]);
                hh.y = pkh(acc[mt][nt][2], acc[mt][nt][3]);
                const size_t base = (((size_t)b * HEADS + h) * P + pos) * 64 + cl2;
                *reinterpret_cast<uint2*>(qh_ + base) = hh;
            }
        }
    } else if (mode == 1) {
        #pragma unroll
        for (int mt = 0; mt < 4; ++mt) {
            const int m0 = mb + 16 * mt + 4 * g;
            const int h = m0 >> 6, cl2 = m0 & 63;
            #pragma unroll
            for (int nt = 0; nt < 2; ++nt) {
                const int pos = nb + 16 * nt + ln;
                uint2 hh;
                hh.x = pkh(acc[mt][nt][0], acc[mt][nt][1]);
                hh.y = pkh(acc[mt][nt][2], acc[mt][nt][3]);
                const size_t base = (((size_t)b * HEADS + h) * PC + pos) * 64 + cl2;
                *reinterpret_cast<uint2*>(kh_ + base) = hh;
            }
        }
    } else {
        #pragma unroll
        for (int mt = 0; mt < 4; ++mt) {
            const int m0 = mb + 16 * mt + 4 * g;   // V channel 0..511
            #pragma unroll
            for (int nt = 0; nt < 2; ++nt) {
                const int pos = nb + 16 * nt + ln;
                #pragma unroll
                for (int r = 0; r < 4; ++r) {
                    unsigned short hv =
                        (unsigned short)(pkh(acc[mt][nt][r], 0.f) & 0xffffu);
                    vh_[((size_t)b * HID + m0 + r) * PC + pos] = hv;
                }
            }
        }
    }
}

// ---------------------------------------------------------------------------
// Flash attention, fixed-max softmax, 1-term S, 1-term PV, LDS P-transpose.
// NEW: manual 2-stage pipeline of the two 32-j halves — half-1's 12 frag
// ds_reads are issued right after half-0's S-MFMAs, draining under half-0's
// softmax+transpose+PV. Named register sets (kfA/vfA, kfB/vfB) bound the
// live set (~170 VGPR < 256 cap from launch_bounds(256,2)).
// ---------------------------------------------------------------------------
#define NIN 4
#define JBLK 64
#define NJT (PC / JBLK)

#define LOADF(HALF, KF, VF) do {                                          \
    _Pragma("unroll")                                                     \
    for (int jm = 0; jm < 2; ++jm)                                        \
        _Pragma("unroll")                                                 \
        for (int ks = 0; ks < 2; ++ks) {                                  \
            const int base_ = (32 * (HALF) + 16 * jm + ln) * 64 +         \
                              8 * ((4 * ks + g) ^ rx);                    \
            KF[jm][ks] = *reinterpret_cast<const f16x8*>(sm + base_);     \
        }                                                                 \
    _Pragma("unroll")                                                     \
    for (int cm = 0; cm < 4; ++cm) {                                      \
        const int vaddr_ = 4096 + (16 * cm + ln) * 64 +                   \
                           8 * ((4 * (HALF) + g) ^ rx);                   \
        VF[cm] = *reinterpret_cast<const f16x8*>(sm + vaddr_);            \
    }                                                                     \
} while (0)

#define SBLOCK(KF) do {                                                   \
    _Pragma("unroll")                                                     \
    for (int jm = 0; jm < 2; ++jm)                                        \
        _Pragma("unroll")                                                 \
        for (int in_ = 0; in_ < NIN; ++in_) {                             \
            f32x4 z = {0.f, 0.f, 0.f, 0.f};                               \
            s[jm][in_] = z;                                               \
        }                                                                 \
    __builtin_amdgcn_s_setprio(1);                                        \
    _Pragma("unroll")                                                     \
    for (int jm = 0; jm < 2; ++jm)                                        \
        _Pragma("unroll")                                                 \
        for (int ks = 0; ks < 2; ++ks)                                    \
            _Pragma("unroll")                                             \
            for (int in_ = 0; in_ < NIN; ++in_)                           \
                s[jm][in_] = MFMA16(KF[jm][ks], qf[in_][ks], s[jm][in_]); \
    __builtin_amdgcn_s_setprio(0);                                        \
} while (0)

#define SMPV(VF) do {                                                     \
    _Pragma("unroll")                                                     \
    for (int in_ = 0; in_ < NIN; ++in_) {                                 \
        float ls = 0.f;                                                   \
        _Pragma("unroll")                                                 \
        for (int jm = 0; jm < 2; ++jm)                                    \
            _Pragma("unroll")                                             \
            for (int r = 0; r < 4; ++r) {                                 \
                float p = EXP2(s[jm][in_][r]);                            \
                s[jm][in_][r] = p; ls += p;                               \
            }                                                             \
        lsum[in_] += ls;                                                  \
        uint32_t w00 = pkh(s[0][in_][0], s[0][in_][1]);                   \
        uint32_t w01 = pkh(s[0][in_][2], s[0][in_][3]);                   \
        uint32_t w10 = pkh(s[1][in_][0], s[1][in_][1]);                   \
        uint32_t w11 = pkh(s[1][in_][2], s[1][in_][3]);                   \
        uint32_t* pw = &pT[wid][ln][0];                                   \
        uint2 wlo; wlo.x = w00; wlo.y = w01;                              \
        uint2 whi; whi.x = w10; whi.y = w11;                              \
        *reinterpret_cast<uint2*>(pw + 2 * g) = wlo;                      \
        *reinterpret_cast<uint2*>(pw + 8 + 2 * g) = whi;                  \
        F8U fu;                                                           \
        u32x4 f4 = *reinterpret_cast<const u32x4*>(&pT[wid][ln][4 * g]);  \
        fu.u[0] = f4[0]; fu.u[1] = f4[1];                                 \
        fu.u[2] = f4[2]; fu.u[3] = f4[3];                                 \
        __builtin_amdgcn_s_setprio(1);                                    \
        _Pragma("unroll")                                                 \
        for (int cm = 0; cm < 4; ++cm)                                    \
            acc[cm][in_] = MFMA16(VF[cm], fu.v, acc[cm][in_]);            \
        __builtin_amdgcn_s_setprio(0);                                    \
    }                                                                     \
} while (0)

__global__ __launch_bounds__(256, 2) void attn_mfma(
    const unsigned short* __restrict__ qh,
    const unsigned short* __restrict__ kh,
    const unsigned short* __restrict__ vh,
    uint32_t* __restrict__ oh)
{
    const int wid = threadIdx.x >> 6;
    const int l = threadIdx.x & 63;
    const int ln = l & 15, g = l >> 4;
    const int rx = ln & 7;
    const int hb = blockIdx.x;                 // (h, b) composite
    const int h = hb & 7, b = hb >> 3;
    const int i0 = (blockIdx.y * 4 + wid) * 64;

    const size_t qbase = (size_t)(b * HEADS + h) * P * 64;
    const size_t kbase = (size_t)(b * HEADS + h) * PC * 64;
    const size_t vbase = (size_t)(b * HID + h * DH) * PC;

    __shared__ unsigned short smem[2][8192];
    __shared__ uint32_t pT[4][16][20];   // per-wave P^T: [wave][col ln][jpair]

    f16x8 qf[NIN][2];
    #pragma unroll
    for (int in_ = 0; in_ < NIN; ++in_) {
        const size_t qrow = qbase + (size_t)(i0 + 16 * in_ + ln) * 64 + 8 * g;
        #pragma unroll
        for (int ks = 0; ks < 2; ++ks)
            qf[in_][ks] = *reinterpret_cast<const f16x8*>(qh + qrow + 32 * ks);
    }

    f32x4 acc[4][NIN];
    #pragma unroll
    for (int cm = 0; cm < 4; ++cm)
        #pragma unroll
        for (int in_ = 0; in_ < NIN; ++in_) {
            f32x4 z = {0.f, 0.f, 0.f, 0.f};
            acc[cm][in_] = z;
        }
    float lsum[NIN];
    #pragma unroll
    for (int in_ = 0; in_ < NIN; ++in_) lsum[in_] = 0.f;

    // staging: 16 segs of 512 hw; wave stages segs wid*4 .. wid*4+3.
    auto stage = [&](int buf, int jt) {
        const int j0 = jt * JBLK;
        #pragma unroll
        for (int t = 0; t < 4; ++t) {
            const int s_ = wid * 4 + t;
            unsigned short* lbase = &smem[buf][s_ * 512];
            const int e = (s_ & 7) * 64 + l;
            const int row = e >> 3, p = e & 7;
            const int slog = p ^ (row & 7);
            const unsigned short* src;
            if (s_ < 8) {
                src = kh + kbase + (size_t)(j0 + row) * 64 + 8 * slog;
            } else {
                src = vh + vbase + (size_t)row * PC + j0 + 8 * slog;
            }
            gl_lds16(src, lbase);
        }
    };

    stage(0, 0);
    __syncthreads();

    for (int jt = 0; jt < NJT; ++jt) {
        const int cur = jt & 1;
        if (jt + 1 < NJT) stage(cur ^ 1, jt + 1);
        const unsigned short* sm = &smem[cur][0];

        f16x8 kfA[2][2], vfA[4], kfB[2][2], vfB[4];
        f32x4 s[2][NIN];

        LOADF(0, kfA, vfA);
        SBLOCK(kfA);           // half-0 S-MFMAs
        LOADF(1, kfB, vfB);    // prefetch half-1 frags under half-0 softmax/PV
        SMPV(vfA);             // half-0 softmax + transpose + PV
        SBLOCK(kfB);           // half-1
        SMPV(vfB);

        __syncthreads();       // one barrier per 64-j tile
    }

    // epilogue: reduce lsum across g-groups, O/l -> fp16 hi, transposed
    #pragma unroll
    for (int in_ = 0; in_ < NIN; ++in_) {
        float lt = lsum[in_];
        lt += __shfl_xor(lt, 16, 64);
        lt += __shfl_xor(lt, 32, 64);
        float inv = 1.0f / lt;
        int i = i0 + 16 * in_ + ln;
        #pragma unroll
        for (int cm = 0; cm < 4; ++cm) {
            f32x4 o4 = acc[cm][in_] * inv;
            const int cp = 32 * h + 8 * cm + 2 * g;
            const size_t idx = ((size_t)b * 256 + cp) * P + i;
            oh[idx] = pkh(o4[0], o4[1]);
            oh[idx + P] = pkh(o4[2], o4[3]);
        }
    }
}

// ---------------------------------------------------------------------------
// Output projection: out = Wo_h @ O_h + bo (1-term fp16 MFMA). (unchanged)
// ---------------------------------------------------------------------------
__global__ __launch_bounds__(256, 4) void out_proj(
    const unsigned short* __restrict__ woh, const uint32_t* __restrict__ oh,
    const float* __restrict__ bo, float* __restrict__ out)
{
    const int wid = threadIdx.x >> 6;
    const int l = threadIdx.x & 63;
    const int ln = l & 15, g = l >> 4;
    const int ibase = blockIdx.x * 128 + wid * 32;
    const int otile = blockIdx.y * 32;
    const int b = blockIdx.z;

    f32x4 acc[2][2];
    #pragma unroll
    for (int mt = 0; mt < 2; ++mt)
        #pragma unroll
        for (int nt = 0; nt < 2; ++nt) {
            f32x4 z = {0.f, 0.f, 0.f, 0.f};
            acc[mt][nt] = z;
        }

    #pragma unroll
    for (int ks = 0; ks < 16; ++ks) {
        const int c0 = 32 * ks + 8 * g;
        const int cp0 = c0 >> 1;
        f16x8 wf[2];
        #pragma unroll
        for (int mt = 0; mt < 2; ++mt)
            wf[mt] = *reinterpret_cast<const f16x8*>(
                woh + (size_t)(otile + 16 * mt + ln) * HID + c0);
        #pragma unroll
        for (int nt = 0; nt < 2; ++nt) {
            const int pos = ibase + 16 * nt + ln;
            const size_t obase = ((size_t)b * 256 + cp0) * P + pos;
            F8U bh;
            bh.u[0] = oh[obase];
            bh.u[1] = oh[obase + P];
            bh.u[2] = oh[obase + 2 * (size_t)P];
            bh.u[3] = oh[obase + 3 * (size_t)P];
            #pragma unroll
            for (int mt = 0; mt < 2; ++mt)
                acc[mt][nt] = MFMA16(wf[mt], bh.v, acc[mt][nt]);
        }
    }

    #pragma unroll
    for (int mt = 0; mt < 2; ++mt)
        #pragma unroll
        for (int r = 0; r < 4; ++r) {
            int o_ = otile + 16 * mt + 4 * g + r;
            float bv = bo[o_];
            #pragma unroll
            for (int nt = 0; nt < 2; ++nt)
                out[((size_t)b * CQ + o_) * P + ibase + 16 * nt + ln] =
                    acc[mt][nt][r] + bv;
        }
}

extern "C" void kernel_launch(void* const* d_in, const int* in_sizes, int n_in,
                              void* d_out, int out_size, void* d_ws, size_t ws_size,
                              hipStream_t stream) {
    (void)in_sizes; (void)n_in; (void)out_size; (void)ws_size;
    const float* x   = (const float*)d_in[0];
    const float* ctx = (const float*)d_in[1];
    const float* Wq  = (const float*)d_in[2];
    const float* Wk  = (const float*)d_in[3];
    const float* Wv  = (const float*)d_in[4];
    const float* Wo  = (const float*)d_in[5];
    const float* bo  = (const float*)d_in[6];
    float* out = (float*)d_out;

    // Workspace (ushort units).
    unsigned short* ws = (unsigned short*)d_ws;
    uint32_t* oh        = (uint32_t*)ws;             // 4194304 u32 = 8388608 us
    unsigned short* qh  = ws + (size_t)8388608;      // 8388608
    unsigned short* kh  = qh + (size_t)8388608;      // 2097152
    unsigned short* vh  = kh + (size_t)2097152;      // 2097152
    unsigned short* woh = vh + (size_t)2097152;      // 131072
    unsigned short* wqh = woh + (size_t)131072;      // 131072
    unsigned short* wkh = wqh + (size_t)131072;      // 262144
    unsigned short* wvh = wkh + (size_t)262144;      // 262144

    dim3 blk(256);
    // 1. weight splits (hi only, octet layout)
    split_all<<<dim3(768), blk, 0, stream>>>(Wq, Wk, Wv, Wo, wqh, wkh, wvh, woh);
    // 2. fused Q/K/V projections (R19 shape)
    proj_qkv<<<dim3(96, 4, BATCH), blk, 0, stream>>>(
        wqh, wkh, wvh, x, ctx, qh, kh, vh);
    // 3. attention -> oh transposed (pipelined halves)
    attn_mfma<<<dim3(HEADS * BATCH, P / 256), blk, 0, stream>>>(
        qh, kh, vh, oh);
    // 4. out = Wo @ O + bo
    out_proj<<<dim3(P / 128, CQ / 32, BATCH), blk, 0, stream>>>(
        woh, oh, bo, out);
}

// Round 23
// 107.254 us; speedup vs baseline: 1.0224x; 1.0224x over previous
//
#include <hip/hip_runtime.h>
#include <math.h>
#include <stdint.h>

// Problem dims (fixed)
#define BATCH 4
#define CQ 256      // x channels
#define P 4096      // query positions (64*64)
#define CC 512      // context channels
#define PC 1024     // kv positions (32*32)
#define HID 512     // HEADS*DIM_HEAD
#define HEADS 8
#define DH 64

// Fold attention scale 1/sqrt(64) * log2(e) into Q so softmax uses exp2.
#define QSCALE 0.180336880111113703f

typedef __attribute__((ext_vector_type(8))) __fp16 f16x8;
typedef __attribute__((ext_vector_type(2))) __fp16 f16x2;
typedef __attribute__((ext_vector_type(4))) float f32x4;
typedef __attribute__((ext_vector_type(4))) unsigned int u32x4;

union H2U { f16x2 h; uint32_t u; };
union F8U { uint32_t u[4]; f16x8 v; };

__device__ __forceinline__ uint32_t pkh(float a, float b) {
    H2U z; z.h = __builtin_amdgcn_cvt_pkrtz(a, b); return z.u;
}
__device__ __forceinline__ f16x2 upk(uint32_t w) { H2U z; z.u = w; return z.h; }

#if __has_builtin(__builtin_amdgcn_exp2f)
#define EXP2(x) __builtin_amdgcn_exp2f(x)
#else
#define EXP2(x) exp2f(x)
#endif

#define MFMA16(a, b, c) __builtin_amdgcn_mfma_f32_16x16x32_f16(a, b, c, 0, 0, 0)

// async global -> LDS, 16B per lane. lds base must be wave-uniform.
__device__ __forceinline__ void gl_lds16(const unsigned short* g, unsigned short* l) {
    __builtin_amdgcn_global_load_lds(
        (const __attribute__((address_space(1))) unsigned int*)g,
        (__attribute__((address_space(3))) unsigned int*)l, 16, 0, 0);
}

// ---------------------------------------------------------------------------
// Split weights, fp16 HI only (float4-vectorized).
// wq/wk/wv -> octet layout [k/8][m][8] (wq pre-scaled by QSCALE);
// wo -> linear [o][c].
// ---------------------------------------------------------------------------
__global__ __launch_bounds__(256) void split_all(
    const float* __restrict__ Wq, const float* __restrict__ Wk,
    const float* __restrict__ Wv, const float* __restrict__ Wo,
    unsigned short* __restrict__ wqh, unsigned short* __restrict__ wkh,
    unsigned short* __restrict__ wvh, unsigned short* __restrict__ woh)
{
    const int bid = blockIdx.x;
    const int t = threadIdx.x;
    const float* src; unsigned short* dh; int i4; float sc = 1.f; int ksh;
    if (bid < 128)      { src = Wq; dh = wqh; i4 = bid * 256 + t; sc = QSCALE; ksh = 8; }
    else if (bid < 384) { src = Wk; dh = wkh; i4 = (bid - 128) * 256 + t; ksh = 9; }
    else if (bid < 640) { src = Wv; dh = wvh; i4 = (bid - 384) * 256 + t; ksh = 9; }
    else                { src = Wo; dh = woh; i4 = (bid - 640) * 256 + t; ksh = 0; }
    float4 v = *reinterpret_cast<const float4*>(src + (size_t)i4 * 4);
    uint2 hh;
    hh.x = pkh(sc * v.x, sc * v.y);
    hh.y = pkh(sc * v.z, sc * v.w);
    if (ksh) {
        const int lin = i4 * 4;
        const int m = lin >> ksh;
        const int k = lin & ((1 << ksh) - 1);
        const size_t off = ((size_t)(k >> 3) * HID + m) * 8 + (k & 7);
        *reinterpret_cast<uint2*>(dh + off) = hh;
    } else {
        *reinterpret_cast<uint2*>(dh + (size_t)i4 * 4) = hh;
    }
}

// ---------------------------------------------------------------------------
// Fused Q + K + V projections, 1-term fp16 MFMA, raw fp32 inputs.
// R19 shape: M=128/block, A-frags ah[4] hoisted before the MFMA cluster.
// blockIdx.x < 64: Q; in [64,96): K (u>>4==0) / V (==1). grid (96,4,B).
// ---------------------------------------------------------------------------
__global__ __launch_bounds__(256) void proj_qkv(
    const unsigned short* __restrict__ wqh_, const unsigned short* __restrict__ wkh_,
    const unsigned short* __restrict__ wvh_,
    const float* __restrict__ x_, const float* __restrict__ ctx_,
    unsigned short* __restrict__ qh_,
    unsigned short* __restrict__ kh_, unsigned short* __restrict__ vh_)
{
    const int b = blockIdx.z;
    const int bx = blockIdx.x;
    const int wid = threadIdx.x >> 6;
    const int l = threadIdx.x & 63;
    const int ln = l & 15, g = l >> 4;
    const int mb = blockIdx.y * 128 + 64 * (wid & 1);

    f32x4 acc[4][2];
    #pragma unroll
    for (int mt = 0; mt < 4; ++mt)
        #pragma unroll
        for (int nt = 0; nt < 2; ++nt) {
            f32x4 z = {0.f, 0.f, 0.f, 0.f};
            acc[mt][nt] = z;
        }

    int mode;        // 0=Q, 1=K, 2=V
    int nb;
    if (bx < 64) {
        mode = 0;
        nb = bx * 64 + 32 * (wid >> 1);
        const float* xb = x_ + (size_t)b * CQ * P;
        #pragma unroll 2
        for (int k0 = 0; k0 < CQ; k0 += 32) {
            const int kq = (k0 >> 3) + g;
            f16x8 ah[4];
            #pragma unroll
            for (int mt = 0; mt < 4; ++mt)
                ah[mt] = *reinterpret_cast<const f16x8*>(
                    wqh_ + ((size_t)kq * HID + mb + 16 * mt + ln) * 8);
            #pragma unroll
            for (int nt = 0; nt < 2; ++nt) {
                const int pos = nb + 16 * nt + ln;
                float v0 = xb[(size_t)(8 * kq + 0) * P + pos];
                float v1 = xb[(size_t)(8 * kq + 1) * P + pos];
                float v2 = xb[(size_t)(8 * kq + 2) * P + pos];
                float v3 = xb[(size_t)(8 * kq + 3) * P + pos];
                float v4 = xb[(size_t)(8 * kq + 4) * P + pos];
                float v5 = xb[(size_t)(8 * kq + 5) * P + pos];
                float v6 = xb[(size_t)(8 * kq + 6) * P + pos];
                float v7 = xb[(size_t)(8 * kq + 7) * P + pos];
                F8U bh;
                bh.u[0] = pkh(v0, v1); bh.u[1] = pkh(v2, v3);
                bh.u[2] = pkh(v4, v5); bh.u[3] = pkh(v6, v7);
                #pragma unroll
                for (int mt = 0; mt < 4; ++mt)
                    acc[mt][nt] = MFMA16(ah[mt], bh.v, acc[mt][nt]);
            }
        }
    } else {
        const int u = bx - 64;
        mode = 1 + (u >> 4);
        nb = (u & 15) * 64 + 32 * (wid >> 1);
        const unsigned short* Ah = (mode == 2) ? wvh_ : wkh_;
        const float* cb = ctx_ + (size_t)b * CC * PC;
        #pragma unroll 2
        for (int k0 = 0; k0 < CC; k0 += 32) {
            const int kq = (k0 >> 3) + g;
            f16x8 ah[4];
            #pragma unroll
            for (int mt = 0; mt < 4; ++mt)
                ah[mt] = *reinterpret_cast<const f16x8*>(
                    Ah + ((size_t)kq * HID + mb + 16 * mt + ln) * 8);
            #pragma unroll
            for (int nt = 0; nt < 2; ++nt) {
                const int pos = nb + 16 * nt + ln;
                float v0 = cb[(size_t)(8 * kq + 0) * PC + pos];
                float v1 = cb[(size_t)(8 * kq + 1) * PC + pos];
                float v2 = cb[(size_t)(8 * kq + 2) * PC + pos];
                float v3 = cb[(size_t)(8 * kq + 3) * PC + pos];
                float v4 = cb[(size_t)(8 * kq + 4) * PC + pos];
                float v5 = cb[(size_t)(8 * kq + 5) * PC + pos];
                float v6 = cb[(size_t)(8 * kq + 6) * PC + pos];
                float v7 = cb[(size_t)(8 * kq + 7) * PC + pos];
                F8U bh;
                bh.u[0] = pkh(v0, v1); bh.u[1] = pkh(v2, v3);
                bh.u[2] = pkh(v4, v5); bh.u[3] = pkh(v6, v7);
                #pragma unroll
                for (int mt = 0; mt < 4; ++mt)
                    acc[mt][nt] = MFMA16(ah[mt], bh.v, acc[mt][nt]);
            }
        }
    }

    if (mode == 0) {
        #pragma unroll
        for (int mt = 0; mt < 4; ++mt) {
            const int m0 = mb + 16 * mt + 4 * g;
            const int h = m0 >> 6, cl2 = m0 & 63;
            #pragma unroll
            for (int nt = 0; nt < 2; ++nt) {
                const int pos = nb + 16 * nt + ln;
                uint2 hh;
                hh.x = pkh(acc[mt][nt][0], acc[mt][nt][1]);
                hh.y = pkh(acc[mt][nt][2], acc[mt][nt][3]);
                const size_t base = (((size_t)b * HEADS + h) * P + pos) * 64 + cl2;
                *reinterpret_cast<uint2*>(qh_ + base) = hh;
            }
        }
    } else if (mode == 1) {
        #pragma unroll
        for (int mt = 0; mt < 4; ++mt) {
            const int m0 = mb + 16 * mt + 4 * g;
            const int h = m0 >> 6, cl2 = m0 & 63;
            #pragma unroll
            for (int nt = 0; nt < 2; ++nt) {
                const int pos = nb + 16 * nt + ln;
                uint2 hh;
                hh.x = pkh(acc[mt][nt][0], acc[mt][nt][1]);
                hh.y = pkh(acc[mt][nt][2], acc[mt][nt][3]);
                const size_t base = (((size_t)b * HEADS + h) * PC + pos) * 64 + cl2;
                *reinterpret_cast<uint2*>(kh_ + base) = hh;
            }
        }
    } else {
        #pragma unroll
        for (int mt = 0; mt < 4; ++mt) {
            const int m0 = mb + 16 * mt + 4 * g;   // V channel 0..511
            #pragma unroll
            for (int nt = 0; nt < 2; ++nt) {
                const int pos = nb + 16 * nt + ln;
                #pragma unroll
                for (int r = 0; r < 4; ++r) {
                    unsigned short hv =
                        (unsigned short)(pkh(acc[mt][nt][r], 0.f) & 0xffffu);
                    vh_[((size_t)b * HID + m0 + r) * PC + pos] = hv;
                }
            }
        }
    }
}

// ---------------------------------------------------------------------------
// Flash attention, fixed-max softmax, 1-term S, 1-term PV.
// P redistribution via per-wave LDS transpose (verified R21: 52 us,
// bit-identical numerics to the shfl form).
// ---------------------------------------------------------------------------
#define NIN 4
#define JBLK 64
#define NJT (PC / JBLK)

__global__ __launch_bounds__(256, 2) void attn_mfma(
    const unsigned short* __restrict__ qh,
    const unsigned short* __restrict__ kh,
    const unsigned short* __restrict__ vh,
    uint32_t* __restrict__ oh)
{
    const int wid = threadIdx.x >> 6;
    const int l = threadIdx.x & 63;
    const int ln = l & 15, g = l >> 4;
    const int rx = ln & 7;
    const int hb = blockIdx.x;                 // (h, b) composite
    const int h = hb & 7, b = hb >> 3;
    const int i0 = (blockIdx.y * 4 + wid) * 64;

    const size_t qbase = (size_t)(b * HEADS + h) * P * 64;
    const size_t kbase = (size_t)(b * HEADS + h) * PC * 64;
    const size_t vbase = (size_t)(b * HID + h * DH) * PC;

    __shared__ unsigned short smem[2][8192];
    __shared__ uint32_t pT[4][16][20];   // per-wave P^T: [wave][col ln][jpair]

    f16x8 qf[NIN][2];
    #pragma unroll
    for (int in_ = 0; in_ < NIN; ++in_) {
        const size_t qrow = qbase + (size_t)(i0 + 16 * in_ + ln) * 64 + 8 * g;
        #pragma unroll
        for (int ks = 0; ks < 2; ++ks)
            qf[in_][ks] = *reinterpret_cast<const f16x8*>(qh + qrow + 32 * ks);
    }

    f32x4 acc[4][NIN];
    #pragma unroll
    for (int cm = 0; cm < 4; ++cm)
        #pragma unroll
        for (int in_ = 0; in_ < NIN; ++in_) {
            f32x4 z = {0.f, 0.f, 0.f, 0.f};
            acc[cm][in_] = z;
        }
    float lsum[NIN];
    #pragma unroll
    for (int in_ = 0; in_ < NIN; ++in_) lsum[in_] = 0.f;

    // staging: 16 segs of 512 hw; wave stages segs wid*4 .. wid*4+3.
    auto stage = [&](int buf, int jt) {
        const int j0 = jt * JBLK;
        #pragma unroll
        for (int t = 0; t < 4; ++t) {
            const int s_ = wid * 4 + t;
            unsigned short* lbase = &smem[buf][s_ * 512];
            const int e = (s_ & 7) * 64 + l;
            const int row = e >> 3, p = e & 7;
            const int slog = p ^ (row & 7);
            const unsigned short* src;
            if (s_ < 8) {
                src = kh + kbase + (size_t)(j0 + row) * 64 + 8 * slog;
            } else {
                src = vh + vbase + (size_t)row * PC + j0 + 8 * slog;
            }
            gl_lds16(src, lbase);
        }
    };

    stage(0, 0);
    __syncthreads();

    for (int jt = 0; jt < NJT; ++jt) {
        const int cur = jt & 1;
        if (jt + 1 < NJT) stage(cur ^ 1, jt + 1);
        const unsigned short* sm = &smem[cur][0];

        #pragma unroll 1
        for (int half = 0; half < 2; ++half) {
            f16x8 kf[2][2];
            #pragma unroll
            for (int jm = 0; jm < 2; ++jm)
                #pragma unroll
                for (int ks = 0; ks < 2; ++ks) {
                    const int base = (32 * half + 16 * jm + ln) * 64 +
                                     8 * ((4 * ks + g) ^ rx);
                    kf[jm][ks] = *reinterpret_cast<const f16x8*>(sm + base);
                }
            f16x8 vf[4];
            #pragma unroll
            for (int cm = 0; cm < 4; ++cm) {
                const int vaddr = 4096 + (16 * cm + ln) * 64 +
                                  8 * ((4 * half + g) ^ rx);
                vf[cm] = *reinterpret_cast<const f16x8*>(sm + vaddr);
            }

            f32x4 s[2][NIN];
            #pragma unroll
            for (int jm = 0; jm < 2; ++jm)
                #pragma unroll
                for (int in_ = 0; in_ < NIN; ++in_) {
                    f32x4 z = {0.f, 0.f, 0.f, 0.f};
                    s[jm][in_] = z;
                }
            __builtin_amdgcn_s_setprio(1);
            #pragma unroll
            for (int jm = 0; jm < 2; ++jm)
                #pragma unroll
                for (int ks = 0; ks < 2; ++ks)
                    #pragma unroll
                    for (int in_ = 0; in_ < NIN; ++in_)
                        s[jm][in_] = MFMA16(kf[jm][ks], qf[in_][ks], s[jm][in_]);
            __builtin_amdgcn_s_setprio(0);

            // fixed-max softmax: P = exp2(s); lsum per-lane partial
            #pragma unroll
            for (int in_ = 0; in_ < NIN; ++in_) {
                float ls = 0.f;
                #pragma unroll
                for (int jm = 0; jm < 2; ++jm)
                    #pragma unroll
                    for (int r = 0; r < 4; ++r) {
                        float p = EXP2(s[jm][in_][r]);
                        s[jm][in_][r] = p; ls += p;
                    }
                lsum[in_] += ls;

                uint32_t w00 = pkh(s[0][in_][0], s[0][in_][1]);
                uint32_t w01 = pkh(s[0][in_][2], s[0][in_][3]);
                uint32_t w10 = pkh(s[1][in_][0], s[1][in_][1]);
                uint32_t w11 = pkh(s[1][in_][2], s[1][in_][3]);

                // P transpose via per-wave LDS (same-wave, no barrier):
                uint32_t* pw = &pT[wid][ln][0];
                uint2 wlo; wlo.x = w00; wlo.y = w01;
                uint2 whi; whi.x = w10; whi.y = w11;
                *reinterpret_cast<uint2*>(pw + 2 * g) = wlo;
                *reinterpret_cast<uint2*>(pw + 8 + 2 * g) = whi;
                F8U fu;
                u32x4 f4 = *reinterpret_cast<const u32x4*>(&pT[wid][ln][4 * g]);
                fu.u[0] = f4[0]; fu.u[1] = f4[1];
                fu.u[2] = f4[2]; fu.u[3] = f4[3];

                __builtin_amdgcn_s_setprio(1);
                #pragma unroll
                for (int cm = 0; cm < 4; ++cm)
                    acc[cm][in_] = MFMA16(vf[cm], fu.v, acc[cm][in_]);
                __builtin_amdgcn_s_setprio(0);
            }
        }

        __syncthreads();   // one barrier per 64-j tile
    }

    // epilogue: reduce lsum across g-groups, O/l -> fp16 hi, transposed
    #pragma unroll
    for (int in_ = 0; in_ < NIN; ++in_) {
        float lt = lsum[in_];
        lt += __shfl_xor(lt, 16, 64);
        lt += __shfl_xor(lt, 32, 64);
        float inv = 1.0f / lt;
        int i = i0 + 16 * in_ + ln;
        #pragma unroll
        for (int cm = 0; cm < 4; ++cm) {
            f32x4 o4 = acc[cm][in_] * inv;
            const int cp = 32 * h + 8 * cm + 2 * g;
            const size_t idx = ((size_t)b * 256 + cp) * P + i;
            oh[idx] = pkh(o4[0], o4[1]);
            oh[idx + P] = pkh(o4[2], o4[3]);
        }
    }
}

// ---------------------------------------------------------------------------
// Output projection: out = Wo_h @ O_h + bo (1-term fp16 MFMA), coalesced
// B-loads from transposed oh [b][cp][pos].
// ---------------------------------------------------------------------------
__global__ __launch_bounds__(256, 4) void out_proj(
    const unsigned short* __restrict__ woh, const uint32_t* __restrict__ oh,
    const float* __restrict__ bo, float* __restrict__ out)
{
    const int wid = threadIdx.x >> 6;
    const int l = threadIdx.x & 63;
    const int ln = l & 15, g = l >> 4;
    const int ibase = blockIdx.x * 128 + wid * 32;
    const int otile = blockIdx.y * 32;
    const int b = blockIdx.z;

    f32x4 acc[2][2];
    #pragma unroll
    for (int mt = 0; mt < 2; ++mt)
        #pragma unroll
        for (int nt = 0; nt < 2; ++nt) {
            f32x4 z = {0.f, 0.f, 0.f, 0.f};
            acc[mt][nt] = z;
        }

    #pragma unroll
    for (int ks = 0; ks < 16; ++ks) {
        const int c0 = 32 * ks + 8 * g;
        const int cp0 = c0 >> 1;
        f16x8 wf[2];
        #pragma unroll
        for (int mt = 0; mt < 2; ++mt)
            wf[mt] = *reinterpret_cast<const f16x8*>(
                woh + (size_t)(otile + 16 * mt + ln) * HID + c0);
        #pragma unroll
        for (int nt = 0; nt < 2; ++nt) {
            const int pos = ibase + 16 * nt + ln;
            const size_t obase = ((size_t)b * 256 + cp0) * P + pos;
            F8U bh;
            bh.u[0] = oh[obase];
            bh.u[1] = oh[obase + P];
            bh.u[2] = oh[obase + 2 * (size_t)P];
            bh.u[3] = oh[obase + 3 * (size_t)P];
            #pragma unroll
            for (int mt = 0; mt < 2; ++mt)
                acc[mt][nt] = MFMA16(wf[mt], bh.v, acc[mt][nt]);
        }
    }

    #pragma unroll
    for (int mt = 0; mt < 2; ++mt)
        #pragma unroll
        for (int r = 0; r < 4; ++r) {
            int o_ = otile + 16 * mt + 4 * g + r;
            float bv = bo[o_];
            #pragma unroll
            for (int nt = 0; nt < 2; ++nt)
                out[((size_t)b * CQ + o_) * P + ibase + 16 * nt + ln] =
                    acc[mt][nt][r] + bv;
        }
}

extern "C" void kernel_launch(void* const* d_in, const int* in_sizes, int n_in,
                              void* d_out, int out_size, void* d_ws, size_t ws_size,
                              hipStream_t stream) {
    (void)in_sizes; (void)n_in; (void)out_size; (void)ws_size;
    const float* x   = (const float*)d_in[0];
    const float* ctx = (const float*)d_in[1];
    const float* Wq  = (const float*)d_in[2];
    const float* Wk  = (const float*)d_in[3];
    const float* Wv  = (const float*)d_in[4];
    const float* Wo  = (const float*)d_in[5];
    const float* bo  = (const float*)d_in[6];
    float* out = (float*)d_out;

    // Workspace (ushort units).
    unsigned short* ws = (unsigned short*)d_ws;
    uint32_t* oh        = (uint32_t*)ws;             // 4194304 u32 = 8388608 us
    unsigned short* qh  = ws + (size_t)8388608;      // 8388608
    unsigned short* kh  = qh + (size_t)8388608;      // 2097152
    unsigned short* vh  = kh + (size_t)2097152;      // 2097152
    unsigned short* woh = vh + (size_t)2097152;      // 131072
    unsigned short* wqh = woh + (size_t)131072;      // 131072
    unsigned short* wkh = wqh + (size_t)131072;      // 262144
    unsigned short* wvh = wkh + (size_t)262144;      // 262144

    dim3 blk(256);
    // 1. weight splits (hi only, octet layout)
    split_all<<<dim3(768), blk, 0, stream>>>(Wq, Wk, Wv, Wo, wqh, wkh, wvh, woh);
    // 2. fused Q/K/V projections (R19 shape)
    proj_qkv<<<dim3(96, 4, BATCH), blk, 0, stream>>>(
        wqh, wkh, wvh, x, ctx, qh, kh, vh);
    // 3. attention -> oh transposed (LDS P-transpose)
    attn_mfma<<<dim3(HEADS * BATCH, P / 256), blk, 0, stream>>>(
        qh, kh, vh, oh);
    // 4. out = Wo @ O + bo
    out_proj<<<dim3(P / 128, CQ / 32, BATCH), blk, 0, stream>>>(
        woh, oh, bo, out);
}